// Round 16
// baseline (329.974 us; speedup 1.0000x reference)
//
#include <hip/hip_runtime.h>
#include <cstdint>
#include <cstddef>

#define ROWS    2048
#define DIM     1024
#define VOCAB   50257
#define CUT0    2000
#define CUT1    10000
#define PROJ_LD 320      // h columns: 256 (cluster0) + 64 (cluster1)
#define LGTC_LD 10016    // compact logit buffer row stride (10000 padded)
#define N1      (VOCAB - CUT1)   // 40257

typedef __attribute__((ext_vector_type(8))) _Float16 f16x8;
typedef __attribute__((ext_vector_type(4))) float    f32x4;
typedef __attribute__((ext_vector_type(4))) unsigned int u32x4;

__device__ __forceinline__ void gload_lds16(const void* g, void* l) {
    __builtin_amdgcn_global_load_lds(
        (const __attribute__((address_space(1))) void*)g,
        (__attribute__((address_space(3))) void*)l, 16, 0, 0);
}

// XCD-aware swizzle (8 XCDs). Requires n % 8 == 0.
__device__ __forceinline__ int swz8(int i, int n) {
    return (i & 7) * (n >> 3) + (i >> 3);
}

// ---------------------------------------------------------------------------
// 32x32 transpose-convert tile job: W[K,N] f32 -> WT[Npad,K] f16.
// ---------------------------------------------------------------------------
__device__ __forceinline__ void transpose_tile(
    const float* __restrict__ src, _Float16* __restrict__ dst,
    int K, int N, int local, int ntiles, float* tile)
{
    const int t  = threadIdx.x;
    const int bn = local % ntiles, bk = local / ntiles;
    const int tx = t & 31, ty = t >> 5;
    const int n0 = bn * 32, k0 = bk * 32;
#pragma unroll
    for (int i = 0; i < 4; ++i) {
        int kk = ty + i * 8;
        int n  = n0 + tx;
        tile[kk * 33 + tx] = (n < N) ? src[(size_t)(k0 + kk) * N + n] : 0.f;
    }
    __syncthreads();
#pragma unroll
    for (int i = 0; i < 4; ++i) {
        int nn = ty + i * 8;
        int r  = n0 + nn;
        dst[(size_t)r * K + k0 + tx] = (_Float16)tile[tx * 33 + nn];
    }
}

// ---------------------------------------------------------------------------
// Kernel 1: all conversions + stats zero.
// ---------------------------------------------------------------------------
__global__ __launch_bounds__(256)
void convert_all(const float* __restrict__ x, const float* __restrict__ head,
                 const float* __restrict__ pk0, const float* __restrict__ pk1,
                 const float* __restrict__ sk0, const float* __restrict__ sk1,
                 _Float16* __restrict__ A, _Float16* __restrict__ headT,
                 _Float16* __restrict__ pkT, _Float16* __restrict__ sk0T,
                 _Float16* __restrict__ sk1T, float* __restrict__ S)
{
    __shared__ float tile[32 * 33];
    const int bid = blockIdx.x, t = threadIdx.x;

    if (bid >= 9016) {                      // zero stats
        int i = (bid - 9016) * 256 + t;     // 2048 float4s
        ((float4*)S)[i] = make_float4(0.f, 0.f, 0.f, 0.f);
        return;
    }
    if (bid < 2048) {                       // flat cast of x
        int fid = bid * 256 + t;
        float4 v = ((const float4*)x)[fid];
        union { _Float16 h[4]; ushort4 u; } cv;
        cv.h[0] = (_Float16)v.x; cv.h[1] = (_Float16)v.y;
        cv.h[2] = (_Float16)v.z; cv.h[3] = (_Float16)v.w;
        ((ushort4*)A)[fid] = cv.u;
        return;
    }
    if (bid < 4096)
        transpose_tile(head, headT, 1024, 2002, bid - 2048, 64, tile);
    else if (bid < 4352)
        transpose_tile(pk0, pkT, 1024, 256, bid - 4096, 8, tile);
    else if (bid < 4480)
        transpose_tile(pk1, pkT + 256 * 1024, 1024, 64, bid - 4352, 4, tile);
    else if (bid < 6496)
        transpose_tile(sk0, sk0T, 256, 8000, bid - 4480, 252, tile);
    else
        transpose_tile(sk1, sk1T, 64, 40257, bid - 6496, 1260, tile);
}

// ---------------------------------------------------------------------------
// 2-phase double-buffered fp16 MFMA GEMM (K=1024: root MODE 0, proj MODE 3).
// Counted vmcnt + raw s_barrier (T3 minimum-2-phase).
// ---------------------------------------------------------------------------
template<int MODE, int BM>
__device__ __forceinline__ void gemm_dbuf(
    _Float16* As, _Float16* Bs,            // As: 2*BM*64, Bs: 2*128*64
    const _Float16* __restrict__ A, int lda,
    const _Float16* __restrict__ B, int K,
    int bx, int by, int Nvalid,
    const float* __restrict__ pb0, const float* __restrict__ pb1,
    _Float16* __restrict__ lgtC, float* __restrict__ root2,
    float* __restrict__ S, _Float16* __restrict__ h)
{
    const int t    = threadIdx.x;
    const int lane = t & 63;
    const int w    = t >> 6;
    const int wr   = w >> 1, wc = w & 1;
    const int q    = lane >> 4, cl = lane & 15;
    const int row0blk = by * BM;
    const int col0blk = bx * 128;
    constexpr int MR   = BM / 32;
    constexpr int NISS = MR + 4;            // staging loads per wave per tile

    // preload proj biases so the K-loop's VMEM is staging-only
    float bn4p[4] = {0.f, 0.f, 0.f, 0.f};
    if (MODE == 3) {
#pragma unroll
        for (int n = 0; n < 4; ++n) {
            int colseg = col0blk + wc * 64 + n * 16 + cl;
            if (colseg < PROJ_LD)
                bn4p[n] = (colseg < 256) ? pb0[colseg] : pb1[colseg - 256];
        }
    }
    __builtin_amdgcn_sched_barrier(0);

    f32x4 acc[MR][4];
#pragma unroll
    for (int m = 0; m < MR; ++m)
#pragma unroll
        for (int n = 0; n < 4; ++n)
            acc[m][n] = (f32x4){0.f, 0.f, 0.f, 0.f};

    auto stage = [&](int bufi, int k0) {
        _Float16* Asb = As + bufi * (BM * 64);
        _Float16* Bsb = Bs + bufi * (128 * 64);
#pragma unroll
        for (int iss = 0; iss < MR; ++iss) {        // A: BM x 64
            int ci  = iss * 256 + w * 64 + lane;
            int row = ci >> 3;
            int ch  = (ci & 7) ^ (row & 7);         // inverse swizzle on source
            gload_lds16(A + (size_t)(row0blk + row) * lda + k0 + ch * 8,
                        Asb + (size_t)(iss * 256 + w * 64) * 8);
        }
#pragma unroll
        for (int iss = 0; iss < 4; ++iss) {         // B: 128 x 64
            int ci  = iss * 256 + w * 64 + lane;
            int row = ci >> 3;
            int ch  = (ci & 7) ^ (row & 7);
            gload_lds16(B + (size_t)(col0blk + row) * K + k0 + ch * 8,
                        Bsb + (size_t)(iss * 256 + w * 64) * 8);
        }
    };

    const int nsteps = K / 64;              // 16
    stage(0, 0);
    int cur = 0;
    for (int ts = 0; ts < nsteps; ++ts) {
        if (ts + 1 < nsteps) {
            stage(cur ^ 1, (ts + 1) * 64);  // prefetch next tile
            asm volatile("s_waitcnt vmcnt(%0)" :: "n"(NISS) : "memory");
        } else {
            asm volatile("s_waitcnt vmcnt(0)" ::: "memory");
        }
        __builtin_amdgcn_s_barrier();       // raw: does NOT drain vmcnt
        __builtin_amdgcn_sched_barrier(0);

        const _Float16* Asb = As + cur * (BM * 64);
        const _Float16* Bsb = Bs + cur * (128 * 64);
#pragma unroll
        for (int kk = 0; kk < 2; ++kk) {
            f16x8 a[MR], b[4];
#pragma unroll
            for (int m = 0; m < MR; ++m) {
                int row = wr * (BM / 2) + m * 16 + cl;
                int ch  = (kk * 4 + q) ^ (row & 7);   // swizzled read
                a[m] = *(const f16x8*)(Asb + row * 64 + ch * 8);
            }
#pragma unroll
            for (int n = 0; n < 4; ++n) {
                int row = wc * 64 + n * 16 + cl;
                int ch  = (kk * 4 + q) ^ (row & 7);
                b[n] = *(const f16x8*)(Bsb + row * 64 + ch * 8);
            }
#pragma unroll
            for (int m = 0; m < MR; ++m)
#pragma unroll
                for (int n = 0; n < 4; ++n)
                    acc[m][n] = __builtin_amdgcn_mfma_f32_16x16x32_f16(
                        a[m], b[n], acc[m][n], 0, 0, 0);
        }
        __builtin_amdgcn_sched_barrier(0);
        __builtin_amdgcn_s_barrier();       // reads done before overwrite
        cur ^= 1;
    }
    __syncthreads();   // full drain; As reusable for reductions

    if (MODE == 3) {   // proj epilogue
#pragma unroll
        for (int m = 0; m < MR; ++m)
#pragma unroll
            for (int n = 0; n < 4; ++n) {
                int colseg = col0blk + wc * 64 + n * 16 + cl;
                if (colseg < PROJ_LD) {
#pragma unroll
                    for (int j = 0; j < 4; ++j) {
                        int rg = row0blk + wr * (BM / 2) + m * 16 + q * 4 + j;
                        h[(size_t)rg * PROJ_LD + colseg] =
                            (_Float16)(acc[m][n][j] + bn4p[n]);
                    }
                }
            }
        return;
    }

    // MODE 0: f16 logit store + Σexp accumulation
    float* sred = (float*)As;
#pragma unroll
    for (int m = 0; m < MR; ++m)
#pragma unroll
        for (int j = 0; j < 4; ++j) {
            int rloc = wr * (BM / 2) + m * 16 + q * 4 + j;
            int rg   = row0blk + rloc;
            float sm = 0.f;
#pragma unroll
            for (int n = 0; n < 4; ++n) {
                int c = col0blk + wc * 64 + n * 16 + cl;
                float v = acc[m][n][j];
                bool ok = c < Nvalid;
                if (ok) {
                    if (c < CUT0)
                        lgtC[(size_t)rg * LGTC_LD + c] = (_Float16)v;
                    else
                        root2[rg * 2 + (c - CUT0)] = v;
                }
                sm += ok ? __expf(v) : 0.f;
            }
#pragma unroll
            for (int d = 1; d < 16; d <<= 1)
                sm += __shfl_xor(sm, d);
            if (cl == 0) sred[wc * BM + rloc] = sm;
        }
    __syncthreads();
    if (t < BM)
        atomicAdd(&S[(row0blk + t) * 4 + 0], sred[t] + sred[BM + t]);
}

// ---------------------------------------------------------------------------
// Single-buffered LDS-staged GEMM body (scale0, K=256, MODE 1).
// ---------------------------------------------------------------------------
template<int MODE, int BM>
__device__ __forceinline__ void gemm_body(
    _Float16* As, _Float16* Bs,
    const _Float16* __restrict__ A, int lda,
    const _Float16* __restrict__ B, int K,
    int bx, int by, int Nvalid,
    const float* __restrict__ bias,
    _Float16* __restrict__ lgtC, const float* __restrict__ root2,
    float* __restrict__ S, float* __restrict__ outF)
{
    const int t    = threadIdx.x;
    const int lane = t & 63;
    const int w    = t >> 6;
    const int wr   = w >> 1, wc = w & 1;
    const int q    = lane >> 4, cl = lane & 15;
    const int row0blk = by * BM;
    const int col0blk = bx * 128;
    constexpr int MR = BM / 32;

    f32x4 acc[MR][4];
#pragma unroll
    for (int m = 0; m < MR; ++m)
#pragma unroll
        for (int n = 0; n < 4; ++n)
            acc[m][n] = (f32x4){0.f, 0.f, 0.f, 0.f};

    for (int k0 = 0; k0 < K; k0 += 64) {
        __syncthreads();
#pragma unroll
        for (int iss = 0; iss < MR; ++iss) {        // A: BM x 64
            int ci  = iss * 256 + w * 64 + lane;
            int row = ci >> 3;
            int ch  = (ci & 7) ^ (row & 7);
            gload_lds16(A + (size_t)(row0blk + row) * lda + k0 + ch * 8,
                        As + (size_t)(iss * 256 + w * 64) * 8);
        }
#pragma unroll
        for (int iss = 0; iss < 4; ++iss) {         // B: 128 x 64
            int ci  = iss * 256 + w * 64 + lane;
            int row = ci >> 3;
            int ch  = (ci & 7) ^ (row & 7);
            gload_lds16(B + (size_t)(col0blk + row) * K + k0 + ch * 8,
                        Bs + (size_t)(iss * 256 + w * 64) * 8);
        }
        __syncthreads();

#pragma unroll
        for (int kk = 0; kk < 2; ++kk) {
            f16x8 a[MR], b[4];
#pragma unroll
            for (int m = 0; m < MR; ++m) {
                int row = wr * (BM / 2) + m * 16 + cl;
                int ch  = (kk * 4 + q) ^ (row & 7);
                a[m] = *(const f16x8*)(As + row * 64 + ch * 8);
            }
#pragma unroll
            for (int n = 0; n < 4; ++n) {
                int row = wc * 64 + n * 16 + cl;
                int ch  = (kk * 4 + q) ^ (row & 7);
                b[n] = *(const f16x8*)(Bs + row * 64 + ch * 8);
            }
#pragma unroll
            for (int m = 0; m < MR; ++m)
#pragma unroll
                for (int n = 0; n < 4; ++n)
                    acc[m][n] = __builtin_amdgcn_mfma_f32_16x16x32_f16(
                        a[m], b[n], acc[m][n], 0, 0, 0);
        }
    }
    __syncthreads();   // LDS reads done; As reusable for reductions

    // bias per column (hoisted)
    float bn4[4];
#pragma unroll
    for (int n = 0; n < 4; ++n) {
        int colseg = col0blk + wc * 64 + n * 16 + cl;
        bn4[n] = (colseg < Nvalid) ? bias[colseg] : 0.f;
    }

    // MODE 1: f16 logit store + Σexp accumulation
    float* sred = (float*)As;
#pragma unroll
    for (int m = 0; m < MR; ++m)
#pragma unroll
        for (int j = 0; j < 4; ++j) {
            int rloc = wr * (BM / 2) + m * 16 + q * 4 + j;
            int rg   = row0blk + rloc;
            float sm = 0.f;
#pragma unroll
            for (int n = 0; n < 4; ++n) {
                int c = col0blk + wc * 64 + n * 16 + cl;
                float v = acc[m][n][j] + bn4[n];
                bool ok = c < Nvalid;
                if (ok)
                    lgtC[(size_t)rg * LGTC_LD + CUT0 + c] = (_Float16)v;
                sm += ok ? __expf(v) : 0.f;
            }
#pragma unroll
            for (int d = 1; d < 16; d <<= 1)
                sm += __shfl_xor(sm, d);
            if (cl == 0) sred[wc * BM + rloc] = sm;
        }
    __syncthreads();
    if (t < BM)
        atomicAdd(&S[(row0blk + t) * 4 + 1], sred[t] + sred[BM + t]);
}

// ---------------------------------------------------------------------------
// B-pinned, A-streaming scale1 GEMM (K=64). One WG per (col-panel, row-group
// of 4 tiles). B (128x64, 16 KB) staged once; A fragments read DIRECTLY from
// L2 (whole A panel = 256 KB). No barriers / vmcnt drains in the tile loop.
// MODE 2: pass1 Σexp (atomics). MODE 4: pass2 direct probability write.
// ---------------------------------------------------------------------------
template<int MODE>
__device__ __forceinline__ void gemm_bpin(
    _Float16* Bs,                          // 128*64
    const _Float16* __restrict__ A,        // h+256, stride PROJ_LD
    const _Float16* __restrict__ B,        // sk1T [40320][64]
    int bx, int g,
    const float* __restrict__ bias,
    const float* __restrict__ root2, float* __restrict__ S,
    float* __restrict__ outF)
{
    const int t    = threadIdx.x;
    const int lane = t & 63;
    const int w    = t >> 6;
    const int wr   = w >> 1, wc = w & 1;
    const int q    = lane >> 4, cl = lane & 15;
    const int col0 = bx * 128;

    // stage B once (128 x 64), proven swizzle
#pragma unroll
    for (int iss = 0; iss < 4; ++iss) {
        int ci  = iss * 256 + w * 64 + lane;
        int row = ci >> 3;
        int ch  = (ci & 7) ^ (row & 7);
        gload_lds16(B + (size_t)(col0 + row) * 64 + ch * 8,
                    Bs + (size_t)(iss * 256 + w * 64) * 8);
    }
    // bias hoist (col panel fixed)
    float bn4[4];
#pragma unroll
    for (int n = 0; n < 4; ++n) {
        int c = col0 + wc * 64 + n * 16 + cl;
        bn4[n] = (c < N1) ? bias[c] : 0.f;
    }
    __syncthreads();                        // B visible to all waves

    for (int ti = 0; ti < 4; ++ti) {
        const int row0 = (g * 4 + ti) * 128;

        f32x4 acc[4][4];
#pragma unroll
        for (int m = 0; m < 4; ++m)
#pragma unroll
            for (int n = 0; n < 4; ++n)
                acc[m][n] = (f32x4){0.f, 0.f, 0.f, 0.f};

#pragma unroll
        for (int kk = 0; kk < 2; ++kk) {
            f16x8 a[4], b[4];
#pragma unroll
            for (int m = 0; m < 4; ++m) {           // A direct from L2
                int row = row0 + wr * 64 + m * 16 + cl;
                a[m] = *(const f16x8*)(A + (size_t)row * PROJ_LD +
                                       kk * 32 + q * 8);
            }
#pragma unroll
            for (int n = 0; n < 4; ++n) {           // B from pinned LDS
                int row = wc * 64 + n * 16 + cl;
                int ch  = (kk * 4 + q) ^ (row & 7);
                b[n] = *(const f16x8*)(Bs + row * 64 + ch * 8);
            }
#pragma unroll
            for (int m = 0; m < 4; ++m)
#pragma unroll
                for (int n = 0; n < 4; ++n)
                    acc[m][n] = __builtin_amdgcn_mfma_f32_16x16x32_f16(
                        a[m], b[n], acc[m][n], 0, 0, 0);
        }

        if (MODE == 2) {        // pass1: Σexp, direct per-row atomics
#pragma unroll
            for (int m = 0; m < 4; ++m)
#pragma unroll
                for (int j = 0; j < 4; ++j) {
                    int rg = row0 + wr * 64 + m * 16 + q * 4 + j;
                    float sm = 0.f;
#pragma unroll
                    for (int n = 0; n < 4; ++n) {
                        int c = col0 + wc * 64 + n * 16 + cl;
                        float v = acc[m][n][j] + bn4[n];
                        sm += (c < N1) ? __expf(v) : 0.f;
                    }
#pragma unroll
                    for (int d = 1; d < 16; d <<= 1)
                        sm += __shfl_xor(sm, d);
                    if (cl == 0) atomicAdd(&S[rg * 4 + 2], sm);
                }
        } else {                // pass2: direct probability write
#pragma unroll
            for (int m = 0; m < 4; ++m)
#pragma unroll
                for (int j = 0; j < 4; ++j) {
                    int rg = row0 + wr * 64 + m * 16 + q * 4 + j;
                    float4 S4 = ((const float4*)S)[rg];
                    float scl = __expf(root2[rg * 2 + 1]) / (S4.z * S4.x);
                    size_t rb = (size_t)rg * VOCAB + CUT1;
#pragma unroll
                    for (int n = 0; n < 4; ++n) {
                        int c = col0 + wc * 64 + n * 16 + cl;
                        if (c < N1)
                            outF[rb + c] = __expf(acc[m][n][j] + bn4[n]) * scl;
                    }
                }
        }
    }
}

// ---------------------------------------------------------------------------
// Kernel 2: root (512 WGs, 64x128, dbuf, first) + proj (96 WGs, 64x128, dbuf).
// BM=64 -> 48 KB LDS -> 3 WG/CU; all 608 WGs in one dispatch round.
// ---------------------------------------------------------------------------
__global__ __launch_bounds__(256)
void k2_projroot(const _Float16* __restrict__ A, const _Float16* __restrict__ pkT,
                 const _Float16* __restrict__ headT,
                 const float* __restrict__ pb0, const float* __restrict__ pb1,
                 _Float16* __restrict__ h, _Float16* __restrict__ lgtC,
                 float* __restrict__ root2, float* __restrict__ S)
{
    __shared__ _Float16 As[2 * 64 * 64];     // 16 KB (BM=64 dbuf)
    __shared__ _Float16 Bs[2 * 128 * 64];    // 32 KB
    const int bid = blockIdx.x;
    if (bid < 512) {
        int i = swz8(bid, 512);
        gemm_dbuf<0, 64>(As, Bs, A, DIM, headT, 1024, i % 16, i / 16, 2002,
                         nullptr, nullptr, lgtC, root2, S, nullptr);
    } else {
        int i = swz8(bid - 512, 96);
        gemm_dbuf<3, 64>(As, Bs, A, DIM, pkT, 1024, i % 3, i / 3, PROJ_LD,
                         pb0, pb1, nullptr, nullptr, nullptr, h);
    }
}

// ---------------------------------------------------------------------------
// Kernel 3: scale0 (1008 WGs, col-major XCD map) + scale1 pass1
// (1260 B-pinned WGs: panel = i>>2, row-group = i&3).
// ---------------------------------------------------------------------------
__global__ __launch_bounds__(256)
void k3_scales(const _Float16* __restrict__ h, const _Float16* __restrict__ sk0T,
               const _Float16* __restrict__ sk1T,
               const float* __restrict__ sb0, const float* __restrict__ sb1,
               _Float16* __restrict__ lgtC, float* __restrict__ S)
{
    __shared__ _Float16 As[128 * 64];
    __shared__ _Float16 Bs[128 * 64];
    const int bid = blockIdx.x;
    if (bid < 1008) {
        int i = swz8(bid, 1008);
        gemm_body<1, 128>(As, Bs, h, PROJ_LD, sk0T, 256, i / 16, i % 16, 8000,
                          sb0, lgtC, nullptr, S, nullptr);
    } else {
        int i = bid - 1008;                  // 0..1259
        gemm_bpin<2>(Bs, h + 256, sk1T, i >> 2, i & 3, sb1, nullptr, S, nullptr);
    }
}

// ---------------------------------------------------------------------------
// Kernel 4: finalize rows FIRST (2048, pure-BW, 16 KB LDS -> high occ) +
// scale1 pass2 (1260 B-pinned WGs, direct out writes).
// ---------------------------------------------------------------------------
__global__ __launch_bounds__(256)
void k4_megafin(const _Float16* __restrict__ h, const _Float16* __restrict__ sk1T,
                const float* __restrict__ sb1, const _Float16* __restrict__ lgtC,
                const float* __restrict__ root2, const float* __restrict__ S,
                float* __restrict__ outF)
{
    __shared__ _Float16 Bs[128 * 64];        // 16 KB only
    const int bid = blockIdx.x;
    if (bid >= 2048) {
        int i = bid - 2048;                  // 0..1259
        gemm_bpin<4>(Bs, h + 256, sk1T, i >> 2, i & 3, sb1, root2,
                     (float*)S, outF);
        return;
    }
    // finalize cols [0,10000): chunk-uniform scale, 16B loads + f32x4 stores
    const int r = bid;
    float4 S4 = ((const float4*)S)[r];
    float inv_r = 1.f / S4.x;
    float sc0   = __expf(root2[r * 2 + 0]) / (S4.y * S4.x);
    const _Float16* lrow = lgtC + (size_t)r * LGTC_LD;
    float* orow = outF + (size_t)r * VOCAB;
    for (int i8 = threadIdx.x; i8 < CUT1 / 8; i8 += 256) {
        u32x4 raw = *(const u32x4*)(lrow + i8 * 8);
        union { uint32_t u; _Float16 hh[2]; } pp[4];
        pp[0].u = raw.x; pp[1].u = raw.y; pp[2].u = raw.z; pp[3].u = raw.w;
        const int c0 = i8 * 8;
        const float sc = (c0 < CUT0) ? inv_r : sc0;
        f32x4 o0, o1;
        o0.x = __expf((float)pp[0].hh[0]) * sc;
        o0.y = __expf((float)pp[0].hh[1]) * sc;
        o0.z = __expf((float)pp[1].hh[0]) * sc;
        o0.w = __expf((float)pp[1].hh[1]) * sc;
        o1.x = __expf((float)pp[2].hh[0]) * sc;
        o1.y = __expf((float)pp[2].hh[1]) * sc;
        o1.z = __expf((float)pp[3].hh[0]) * sc;
        o1.w = __expf((float)pp[3].hh[1]) * sc;
        *(f32x4*)(orow + c0)     = o0;
        *(f32x4*)(orow + c0 + 4) = o1;
    }
}

// ---------------------------------------------------------------------------
extern "C" void kernel_launch(void* const* d_in, const int* in_sizes, int n_in,
                              void* d_out, int out_size, void* d_ws, size_t ws_size,
                              hipStream_t stream)
{
    (void)in_sizes; (void)n_in; (void)out_size; (void)ws_size;

    const float* x    = (const float*)d_in[0];
    const float* head = (const float*)d_in[2];
    const float* pk0  = (const float*)d_in[3];
    const float* pb0  = (const float*)d_in[4];
    const float* sk0  = (const float*)d_in[5];
    const float* sb0  = (const float*)d_in[6];
    const float* pk1  = (const float*)d_in[7];
    const float* pb1  = (const float*)d_in[8];
    const float* sk1  = (const float*)d_in[9];
    const float* sb1  = (const float*)d_in[10];

    float* out = (float*)d_out;
    char*  ws  = (char*)d_ws;

    // ws layout (bytes, all 256-aligned)
    _Float16* lgtC  = (_Float16*)(ws);                 // 2048x10016 f16
    _Float16* A     = (_Float16*)(ws + 41025536);      // 2048x1024
    _Float16* headT = (_Float16*)(ws + 45219840);      // 2048x1024
    _Float16* pkT   = (_Float16*)(ws + 49414144);      // 384x1024
    _Float16* sk0T  = (_Float16*)(ws + 50200576);      // 8064x256
    _Float16* sk1T  = (_Float16*)(ws + 54329344);      // 40320x64
    _Float16* h     = (_Float16*)(ws + 59490304);      // 2048x320
    float*    root2 = (float*)(ws + 60801024);         // 2048x2
    float*    S     = (float*)(ws + 60817408);         // 2048x4 {Sr,S0,S1,-}

    const dim3 blk(256);

    convert_all<<<dim3(9024), blk, 0, stream>>>(x, head, pk0, pk1, sk0, sk1,
                                                A, headT, pkT, sk0T, sk1T, S);
    k2_projroot<<<dim3(608), blk, 0, stream>>>(A, pkT, headT, pb0, pb1,
                                               h, lgtC, root2, S);
    k3_scales<<<dim3(2268), blk, 0, stream>>>(h, sk0T, sk1T, sb0, sb1, lgtC, S);
    k4_megafin<<<dim3(3308), blk, 0, stream>>>(h, sk1T, sb1, lgtC, root2, S, out);
}

// Round 17
// 217.295 us; speedup vs baseline: 1.5186x; 1.5186x over previous
//
#include <hip/hip_runtime.h>
#include <cstdint>
#include <cstddef>

#define ROWS    2048
#define DIM     1024
#define VOCAB   50257
#define CUT0    2000
#define CUT1    10000
#define PROJ_LD 320      // h columns: 256 (cluster0) + 64 (cluster1)
#define LGTC_LD 10016    // compact logit buffer row stride (10000 padded)

typedef __attribute__((ext_vector_type(8))) _Float16 f16x8;
typedef __attribute__((ext_vector_type(4))) float    f32x4;
typedef __attribute__((ext_vector_type(4))) unsigned int u32x4;

__device__ __forceinline__ void gload_lds16(const void* g, void* l) {
    __builtin_amdgcn_global_load_lds(
        (const __attribute__((address_space(1))) void*)g,
        (__attribute__((address_space(3))) void*)l, 16, 0, 0);
}

// XCD-aware swizzle (8 XCDs). Requires n % 8 == 0.
__device__ __forceinline__ int swz8(int i, int n) {
    return (i & 7) * (n >> 3) + (i >> 3);
}

// ---------------------------------------------------------------------------
// 32x32 transpose-convert tile job: W[K,N] f32 -> WT[Npad,K] f16.
// ---------------------------------------------------------------------------
__device__ __forceinline__ void transpose_tile(
    const float* __restrict__ src, _Float16* __restrict__ dst,
    int K, int N, int local, int ntiles, float* tile)
{
    const int t  = threadIdx.x;
    const int bn = local % ntiles, bk = local / ntiles;
    const int tx = t & 31, ty = t >> 5;
    const int n0 = bn * 32, k0 = bk * 32;
#pragma unroll
    for (int i = 0; i < 4; ++i) {
        int kk = ty + i * 8;
        int n  = n0 + tx;
        tile[kk * 33 + tx] = (n < N) ? src[(size_t)(k0 + kk) * N + n] : 0.f;
    }
    __syncthreads();
#pragma unroll
    for (int i = 0; i < 4; ++i) {
        int nn = ty + i * 8;
        int r  = n0 + nn;
        dst[(size_t)r * K + k0 + tx] = (_Float16)tile[tx * 33 + nn];
    }
}

// ---------------------------------------------------------------------------
// Kernel 1: all conversions + stats zero.
// ---------------------------------------------------------------------------
__global__ __launch_bounds__(256)
void convert_all(const float* __restrict__ x, const float* __restrict__ head,
                 const float* __restrict__ pk0, const float* __restrict__ pk1,
                 const float* __restrict__ sk0, const float* __restrict__ sk1,
                 _Float16* __restrict__ A, _Float16* __restrict__ headT,
                 _Float16* __restrict__ pkT, _Float16* __restrict__ sk0T,
                 _Float16* __restrict__ sk1T, float* __restrict__ S)
{
    __shared__ float tile[32 * 33];
    const int bid = blockIdx.x, t = threadIdx.x;

    if (bid >= 9016) {                      // zero stats
        int i = (bid - 9016) * 256 + t;     // 2048 float4s
        ((float4*)S)[i] = make_float4(0.f, 0.f, 0.f, 0.f);
        return;
    }
    if (bid < 2048) {                       // flat cast of x
        int fid = bid * 256 + t;
        float4 v = ((const float4*)x)[fid];
        union { _Float16 h[4]; ushort4 u; } cv;
        cv.h[0] = (_Float16)v.x; cv.h[1] = (_Float16)v.y;
        cv.h[2] = (_Float16)v.z; cv.h[3] = (_Float16)v.w;
        ((ushort4*)A)[fid] = cv.u;
        return;
    }
    if (bid < 4096)
        transpose_tile(head, headT, 1024, 2002, bid - 2048, 64, tile);
    else if (bid < 4352)
        transpose_tile(pk0, pkT, 1024, 256, bid - 4096, 8, tile);
    else if (bid < 4480)
        transpose_tile(pk1, pkT + 256 * 1024, 1024, 64, bid - 4352, 4, tile);
    else if (bid < 6496)
        transpose_tile(sk0, sk0T, 256, 8000, bid - 4480, 252, tile);
    else
        transpose_tile(sk1, sk1T, 64, 40257, bid - 6496, 1260, tile);
}

// ---------------------------------------------------------------------------
// 2-phase double-buffered fp16 MFMA GEMM (K=1024: root MODE 0, proj MODE 3).
// Counted vmcnt + raw s_barrier (T3 minimum-2-phase).
// ---------------------------------------------------------------------------
template<int MODE, int BM>
__device__ __forceinline__ void gemm_dbuf(
    _Float16* As, _Float16* Bs,            // As: 2*BM*64, Bs: 2*128*64
    const _Float16* __restrict__ A, int lda,
    const _Float16* __restrict__ B, int K,
    int bx, int by, int Nvalid,
    const float* __restrict__ pb0, const float* __restrict__ pb1,
    _Float16* __restrict__ lgtC, float* __restrict__ root2,
    float* __restrict__ S, _Float16* __restrict__ h)
{
    const int t    = threadIdx.x;
    const int lane = t & 63;
    const int w    = t >> 6;
    const int wr   = w >> 1, wc = w & 1;
    const int q    = lane >> 4, cl = lane & 15;
    const int row0blk = by * BM;
    const int col0blk = bx * 128;
    constexpr int MR   = BM / 32;
    constexpr int NISS = MR + 4;            // staging loads per wave per tile

    // preload proj biases so the K-loop's VMEM is staging-only
    float bn4p[4] = {0.f, 0.f, 0.f, 0.f};
    if (MODE == 3) {
#pragma unroll
        for (int n = 0; n < 4; ++n) {
            int colseg = col0blk + wc * 64 + n * 16 + cl;
            if (colseg < PROJ_LD)
                bn4p[n] = (colseg < 256) ? pb0[colseg] : pb1[colseg - 256];
        }
    }
    __builtin_amdgcn_sched_barrier(0);

    f32x4 acc[MR][4];
#pragma unroll
    for (int m = 0; m < MR; ++m)
#pragma unroll
        for (int n = 0; n < 4; ++n)
            acc[m][n] = (f32x4){0.f, 0.f, 0.f, 0.f};

    auto stage = [&](int bufi, int k0) {
        _Float16* Asb = As + bufi * (BM * 64);
        _Float16* Bsb = Bs + bufi * (128 * 64);
#pragma unroll
        for (int iss = 0; iss < MR; ++iss) {        // A: BM x 64
            int ci  = iss * 256 + w * 64 + lane;
            int row = ci >> 3;
            int ch  = (ci & 7) ^ (row & 7);         // inverse swizzle on source
            gload_lds16(A + (size_t)(row0blk + row) * lda + k0 + ch * 8,
                        Asb + (size_t)(iss * 256 + w * 64) * 8);
        }
#pragma unroll
        for (int iss = 0; iss < 4; ++iss) {         // B: 128 x 64
            int ci  = iss * 256 + w * 64 + lane;
            int row = ci >> 3;
            int ch  = (ci & 7) ^ (row & 7);
            gload_lds16(B + (size_t)(col0blk + row) * K + k0 + ch * 8,
                        Bsb + (size_t)(iss * 256 + w * 64) * 8);
        }
    };

    const int nsteps = K / 64;              // 16
    stage(0, 0);
    int cur = 0;
    for (int ts = 0; ts < nsteps; ++ts) {
        if (ts + 1 < nsteps) {
            stage(cur ^ 1, (ts + 1) * 64);  // prefetch next tile
            asm volatile("s_waitcnt vmcnt(%0)" :: "n"(NISS) : "memory");
        } else {
            asm volatile("s_waitcnt vmcnt(0)" ::: "memory");
        }
        __builtin_amdgcn_s_barrier();       // raw: does NOT drain vmcnt
        __builtin_amdgcn_sched_barrier(0);

        const _Float16* Asb = As + cur * (BM * 64);
        const _Float16* Bsb = Bs + cur * (128 * 64);
#pragma unroll
        for (int kk = 0; kk < 2; ++kk) {
            f16x8 a[MR], b[4];
#pragma unroll
            for (int m = 0; m < MR; ++m) {
                int row = wr * (BM / 2) + m * 16 + cl;
                int ch  = (kk * 4 + q) ^ (row & 7);   // swizzled read
                a[m] = *(const f16x8*)(Asb + row * 64 + ch * 8);
            }
#pragma unroll
            for (int n = 0; n < 4; ++n) {
                int row = wc * 64 + n * 16 + cl;
                int ch  = (kk * 4 + q) ^ (row & 7);
                b[n] = *(const f16x8*)(Bsb + row * 64 + ch * 8);
            }
#pragma unroll
            for (int m = 0; m < MR; ++m)
#pragma unroll
                for (int n = 0; n < 4; ++n)
                    acc[m][n] = __builtin_amdgcn_mfma_f32_16x16x32_f16(
                        a[m], b[n], acc[m][n], 0, 0, 0);
        }
        __builtin_amdgcn_sched_barrier(0);
        __builtin_amdgcn_s_barrier();       // reads done before overwrite
        cur ^= 1;
    }
    __syncthreads();   // full drain; As reusable for reductions

    if (MODE == 3) {   // proj epilogue
#pragma unroll
        for (int m = 0; m < MR; ++m)
#pragma unroll
            for (int n = 0; n < 4; ++n) {
                int colseg = col0blk + wc * 64 + n * 16 + cl;
                if (colseg < PROJ_LD) {
#pragma unroll
                    for (int j = 0; j < 4; ++j) {
                        int rg = row0blk + wr * (BM / 2) + m * 16 + q * 4 + j;
                        h[(size_t)rg * PROJ_LD + colseg] =
                            (_Float16)(acc[m][n][j] + bn4p[n]);
                    }
                }
            }
        return;
    }

    // MODE 0: f16 logit store + Σexp accumulation
    float* sred = (float*)As;
#pragma unroll
    for (int m = 0; m < MR; ++m)
#pragma unroll
        for (int j = 0; j < 4; ++j) {
            int rloc = wr * (BM / 2) + m * 16 + q * 4 + j;
            int rg   = row0blk + rloc;
            float sm = 0.f;
#pragma unroll
            for (int n = 0; n < 4; ++n) {
                int c = col0blk + wc * 64 + n * 16 + cl;
                float v = acc[m][n][j];
                bool ok = c < Nvalid;
                if (ok) {
                    if (c < CUT0)
                        lgtC[(size_t)rg * LGTC_LD + c] = (_Float16)v;
                    else
                        root2[rg * 2 + (c - CUT0)] = v;
                }
                sm += ok ? __expf(v) : 0.f;
            }
#pragma unroll
            for (int d = 1; d < 16; d <<= 1)
                sm += __shfl_xor(sm, d);
            if (cl == 0) sred[wc * BM + rloc] = sm;
        }
    __syncthreads();
    if (t < BM)
        atomicAdd(&S[(row0blk + t) * 4 + 0], sred[t] + sred[BM + t]);
}

// ---------------------------------------------------------------------------
// Single-buffered LDS-staged GEMM body (small-K cases).
// MODE 1: scale0 -> lgtC f16 + bias + atomic S[r][1]
// MODE 2: scale1 pass1 -> bias + atomic S[r][2] only (no stores)
// MODE 4: scale1 pass2 -> out = exp(l)*scale directly (f32)
// ---------------------------------------------------------------------------
template<int MODE, int BM>
__device__ __forceinline__ void gemm_body(
    _Float16* As, _Float16* Bs,
    const _Float16* __restrict__ A, int lda,
    const _Float16* __restrict__ B, int K,
    int bx, int by, int Nvalid,
    const float* __restrict__ bias,
    _Float16* __restrict__ lgtC, const float* __restrict__ root2,
    float* __restrict__ S, float* __restrict__ outF)
{
    const int t    = threadIdx.x;
    const int lane = t & 63;
    const int w    = t >> 6;
    const int wr   = w >> 1, wc = w & 1;
    const int q    = lane >> 4, cl = lane & 15;
    const int row0blk = by * BM;
    const int col0blk = bx * 128;
    constexpr int MR = BM / 32;

    f32x4 acc[MR][4];
#pragma unroll
    for (int m = 0; m < MR; ++m)
#pragma unroll
        for (int n = 0; n < 4; ++n)
            acc[m][n] = (f32x4){0.f, 0.f, 0.f, 0.f};

    for (int k0 = 0; k0 < K; k0 += 64) {
        __syncthreads();
#pragma unroll
        for (int iss = 0; iss < MR; ++iss) {        // A: BM x 64
            int ci  = iss * 256 + w * 64 + lane;
            int row = ci >> 3;
            int ch  = (ci & 7) ^ (row & 7);
            gload_lds16(A + (size_t)(row0blk + row) * lda + k0 + ch * 8,
                        As + (size_t)(iss * 256 + w * 64) * 8);
        }
#pragma unroll
        for (int iss = 0; iss < 4; ++iss) {         // B: 128 x 64
            int ci  = iss * 256 + w * 64 + lane;
            int row = ci >> 3;
            int ch  = (ci & 7) ^ (row & 7);
            gload_lds16(B + (size_t)(col0blk + row) * K + k0 + ch * 8,
                        Bs + (size_t)(iss * 256 + w * 64) * 8);
        }
        __syncthreads();

#pragma unroll
        for (int kk = 0; kk < 2; ++kk) {
            f16x8 a[MR], b[4];
#pragma unroll
            for (int m = 0; m < MR; ++m) {
                int row = wr * (BM / 2) + m * 16 + cl;
                int ch  = (kk * 4 + q) ^ (row & 7);
                a[m] = *(const f16x8*)(As + row * 64 + ch * 8);
            }
#pragma unroll
            for (int n = 0; n < 4; ++n) {
                int row = wc * 64 + n * 16 + cl;
                int ch  = (kk * 4 + q) ^ (row & 7);
                b[n] = *(const f16x8*)(Bs + row * 64 + ch * 8);
            }
#pragma unroll
            for (int m = 0; m < MR; ++m)
#pragma unroll
                for (int n = 0; n < 4; ++n)
                    acc[m][n] = __builtin_amdgcn_mfma_f32_16x16x32_f16(
                        a[m], b[n], acc[m][n], 0, 0, 0);
        }
    }
    __syncthreads();   // LDS reads done; As reusable for reductions

    // bias per column (hoisted)
    float bn4[4];
#pragma unroll
    for (int n = 0; n < 4; ++n) {
        int colseg = col0blk + wc * 64 + n * 16 + cl;
        bn4[n] = (colseg < Nvalid) ? bias[colseg] : 0.f;
    }

    if (MODE == 4) {   // scale1 pass2: direct probability write
#pragma unroll
        for (int m = 0; m < MR; ++m)
#pragma unroll
            for (int j = 0; j < 4; ++j) {
                int rg = row0blk + wr * (BM / 2) + m * 16 + q * 4 + j;
                float4 S4 = ((const float4*)S)[rg];
                float scl = __expf(root2[rg * 2 + 1]) / (S4.z * S4.x);
                size_t rb = (size_t)rg * VOCAB + CUT1;
#pragma unroll
                for (int n = 0; n < 4; ++n) {
                    int c = col0blk + wc * 64 + n * 16 + cl;
                    if (c < Nvalid)
                        outF[rb + c] = __expf(acc[m][n][j] + bn4[n]) * scl;
                }
            }
        return;
    }

    // MODES 1/2: optional f16 logit store + Σexp accumulation
    float* sred = (float*)As;
#pragma unroll
    for (int m = 0; m < MR; ++m)
#pragma unroll
        for (int j = 0; j < 4; ++j) {
            int rloc = wr * (BM / 2) + m * 16 + q * 4 + j;
            int rg   = row0blk + rloc;
            float sm = 0.f;
#pragma unroll
            for (int n = 0; n < 4; ++n) {
                int c = col0blk + wc * 64 + n * 16 + cl;
                float v = acc[m][n][j] + bn4[n];
                bool ok = c < Nvalid;
                if (MODE == 1 && ok)
                    lgtC[(size_t)rg * LGTC_LD + CUT0 + c] = (_Float16)v;
                sm += ok ? __expf(v) : 0.f;
            }
#pragma unroll
            for (int d = 1; d < 16; d <<= 1)
                sm += __shfl_xor(sm, d);
            if (cl == 0) sred[wc * BM + rloc] = sm;
        }
    __syncthreads();
    if (t < BM) {
        const int sidx = (MODE == 1) ? 1 : 2;
        atomicAdd(&S[(row0blk + t) * 4 + sidx], sred[t] + sred[BM + t]);
    }
}

// ---------------------------------------------------------------------------
// Kernel 2: root (512 WGs, 64x128, dbuf, first) + proj (96 WGs, 64x128, dbuf).
// BM=64 everywhere -> LDS 48 KB -> 3 WG/CU (768 slots): all 608 WGs in one
// dispatch round with extra co-residency for the latency-exposed root.
// ---------------------------------------------------------------------------
__global__ __launch_bounds__(256)
void k2_projroot(const _Float16* __restrict__ A, const _Float16* __restrict__ pkT,
                 const _Float16* __restrict__ headT,
                 const float* __restrict__ pb0, const float* __restrict__ pb1,
                 _Float16* __restrict__ h, _Float16* __restrict__ lgtC,
                 float* __restrict__ root2, float* __restrict__ S)
{
    __shared__ _Float16 As[2 * 64 * 64];     // 16 KB (BM=64 dbuf)
    __shared__ _Float16 Bs[2 * 128 * 64];    // 32 KB
    const int bid = blockIdx.x;
    if (bid < 512) {
        int i = swz8(bid, 512);
        gemm_dbuf<0, 64>(As, Bs, A, DIM, headT, 1024, i % 16, i / 16, 2002,
                         nullptr, nullptr, lgtC, root2, S, nullptr);
    } else {
        int i = swz8(bid - 512, 96);
        gemm_dbuf<3, 64>(As, Bs, A, DIM, pkT, 1024, i % 3, i / 3, PROJ_LD,
                         pb0, pb1, nullptr, nullptr, nullptr, h);
    }
}

// ---------------------------------------------------------------------------
// Kernel 3: scale0 (1008 WGs) + scale1 pass1 (5040 WGs).
// Col-major tile->XCD mapping: each XCD keeps its B-panel L2-resident
// (r12 evidence: k4 FETCH_SIZE only 24 MB with this mapping).
// ---------------------------------------------------------------------------
__global__ __launch_bounds__(256)
void k3_scales(const _Float16* __restrict__ h, const _Float16* __restrict__ sk0T,
               const _Float16* __restrict__ sk1T,
               const float* __restrict__ sb0, const float* __restrict__ sb1,
               _Float16* __restrict__ lgtC, float* __restrict__ S)
{
    __shared__ _Float16 As[128 * 64];
    __shared__ _Float16 Bs[128 * 64];
    const int bid = blockIdx.x;
    if (bid < 1008) {
        int i = swz8(bid, 1008);
        gemm_body<1, 128>(As, Bs, h, PROJ_LD, sk0T, 256, i / 16, i % 16, 8000,
                          sb0, lgtC, nullptr, S, nullptr);
    } else {
        int i = swz8(bid - 1008, 5040);
        gemm_body<2, 128>(As, Bs, h + 256, PROJ_LD, sk1T, 64, i / 16, i % 16,
                          40257, sb1, nullptr, nullptr, S, nullptr);
    }
}

// ---------------------------------------------------------------------------
// Kernel 4: finalize rows FIRST (2048, pure-BW) + scale1 pass2 (5040,
// col-major XCD mapping, plain coalesced writes).
// ---------------------------------------------------------------------------
__global__ __launch_bounds__(256)
void k4_megafin(const _Float16* __restrict__ h, const _Float16* __restrict__ sk1T,
                const float* __restrict__ sb1, const _Float16* __restrict__ lgtC,
                const float* __restrict__ root2, const float* __restrict__ S,
                float* __restrict__ outF)
{
    __shared__ _Float16 As[128 * 64];
    __shared__ _Float16 Bs[128 * 64];
    const int bid = blockIdx.x;
    if (bid >= 2048) {
        int i = swz8(bid - 2048, 5040);
        gemm_body<4, 128>(As, Bs, h + 256, PROJ_LD, sk1T, 64, i / 16, i % 16,
                          40257, sb1, nullptr, root2, (float*)S, outF);
        return;
    }
    // finalize cols [0,10000): chunk-uniform scale, 16B loads + f32x4 stores
    const int r = bid;
    float4 S4 = ((const float4*)S)[r];
    float inv_r = 1.f / S4.x;
    float sc0   = __expf(root2[r * 2 + 0]) / (S4.y * S4.x);
    const _Float16* lrow = lgtC + (size_t)r * LGTC_LD;
    float* orow = outF + (size_t)r * VOCAB;
    for (int i8 = threadIdx.x; i8 < CUT1 / 8; i8 += 256) {
        u32x4 raw = *(const u32x4*)(lrow + i8 * 8);
        union { uint32_t u; _Float16 hh[2]; } pp[4];
        pp[0].u = raw.x; pp[1].u = raw.y; pp[2].u = raw.z; pp[3].u = raw.w;
        const int c0 = i8 * 8;
        const float sc = (c0 < CUT0) ? inv_r : sc0;
        f32x4 o0, o1;
        o0.x = __expf((float)pp[0].hh[0]) * sc;
        o0.y = __expf((float)pp[0].hh[1]) * sc;
        o0.z = __expf((float)pp[1].hh[0]) * sc;
        o0.w = __expf((float)pp[1].hh[1]) * sc;
        o1.x = __expf((float)pp[2].hh[0]) * sc;
        o1.y = __expf((float)pp[2].hh[1]) * sc;
        o1.z = __expf((float)pp[3].hh[0]) * sc;
        o1.w = __expf((float)pp[3].hh[1]) * sc;
        *(f32x4*)(orow + c0)     = o0;
        *(f32x4*)(orow + c0 + 4) = o1;
    }
}

// ---------------------------------------------------------------------------
extern "C" void kernel_launch(void* const* d_in, const int* in_sizes, int n_in,
                              void* d_out, int out_size, void* d_ws, size_t ws_size,
                              hipStream_t stream)
{
    (void)in_sizes; (void)n_in; (void)out_size; (void)ws_size;

    const float* x    = (const float*)d_in[0];
    const float* head = (const float*)d_in[2];
    const float* pk0  = (const float*)d_in[3];
    const float* pb0  = (const float*)d_in[4];
    const float* sk0  = (const float*)d_in[5];
    const float* sb0  = (const float*)d_in[6];
    const float* pk1  = (const float*)d_in[7];
    const float* pb1  = (const float*)d_in[8];
    const float* sk1  = (const float*)d_in[9];
    const float* sb1  = (const float*)d_in[10];

    float* out = (float*)d_out;
    char*  ws  = (char*)d_ws;

    // ws layout (bytes, all 256-aligned)
    _Float16* lgtC  = (_Float16*)(ws);                 // 2048x10016 f16
    _Float16* A     = (_Float16*)(ws + 41025536);      // 2048x1024
    _Float16* headT = (_Float16*)(ws + 45219840);      // 2048x1024
    _Float16* pkT   = (_Float16*)(ws + 49414144);      // 384x1024
    _Float16* sk0T  = (_Float16*)(ws + 50200576);      // 8064x256
    _Float16* sk1T  = (_Float16*)(ws + 54329344);      // 40320x64
    _Float16* h     = (_Float16*)(ws + 59490304);      // 2048x320
    float*    root2 = (float*)(ws + 60801024);         // 2048x2
    float*    S     = (float*)(ws + 60817408);         // 2048x4 {Sr,S0,S1,-}

    const dim3 blk(256);

    convert_all<<<dim3(9024), blk, 0, stream>>>(x, head, pk0, pk1, sk0, sk1,
                                                A, headT, pkT, sk0T, sk1T, S);
    k2_projroot<<<dim3(608), blk, 0, stream>>>(A, pkT, headT, pb0, pb1,
                                               h, lgtC, root2, S);
    k3_scales<<<dim3(6048), blk, 0, stream>>>(h, sk0T, sk1T, sb0, sb1, lgtC, S);
    k4_megafin<<<dim3(7088), blk, 0, stream>>>(h, sk1T, sb1, lgtC, root2, S, out);
}